// Round 4
// baseline (414.828 us; speedup 1.0000x reference)
//
#include <hip/hip_runtime.h>
#include <hip/hip_cooperative_groups.h>
#include <math.h>

namespace cg = cooperative_groups;

// GCN layer: agg = D^-1/2 (A w) D^-1/2 x + x ; out = LayerNorm(gelu(agg @ W + b))
// N=10000, E=640000, D=128. fp32 in/out; edge_index int32.
//
// R4: entire CSR build (bucket count -> scan -> scatter -> per-bucket CSR ->
// xscale) in ONE cooperative kernel with grid.sync between phases (removes 5
// launch gaps + memset dispatch, keeps edges L2-hot). fused_node: per-wave
// CONTIGUOUS edge chunks (uniform fin addresses -> scalar loads) + 16-deep
// gather unroll for 2x memory-level parallelism.

#define D 128
#define NBMAX 256     // max buckets (N <= 16384)
#define BLK 256
#define GRID_BUILD 512

static __device__ __forceinline__ unsigned int bf16bits(float v) {
    unsigned int u = __float_as_uint(v);
    return (u + 0x7fffu + ((u >> 16) & 1u)) >> 16;
}

// ---- K1 (cooperative): full CSR build + deginv + xs ----
__global__ __launch_bounds__(BLK) void build_all(
    const float* __restrict__ x, const int* __restrict__ srcIdx,
    const int* __restrict__ dstIdx, const float* __restrict__ ew,
    int* __restrict__ bucketcnt, int* __restrict__ bucketptr,
    int* __restrict__ bucketcur, uint2* __restrict__ tmp,
    unsigned int* __restrict__ fin, int* __restrict__ rowptr,
    float* __restrict__ deginv, unsigned int* __restrict__ xs,
    int N, int E, int NB) {
    cg::grid_group grid = cg::this_grid();
    __shared__ int hist[NBMAX];
    __shared__ int base[NBMAX];
    int t = threadIdx.x;
    int bid = blockIdx.x;
    int gstride = gridDim.x * BLK;

    // phase 0: zero global bucket counters
    if (bid == 0) bucketcnt[t] = 0;
    hist[t] = 0;
    grid.sync();

    // phase 1: bucket histogram (bucket = dst>>6)
    for (int e = bid * BLK + t; e < E; e += gstride)
        atomicAdd(&hist[dstIdx[e] >> 6], 1);
    __syncthreads();
    if (hist[t]) atomicAdd(&bucketcnt[t], hist[t]);
    grid.sync();

    // phase 2: exclusive scan of bucket counts (block 0 only)
    if (bid == 0) {
        int v = bucketcnt[t];
        hist[t] = v;
        __syncthreads();
        for (int o = 1; o < NBMAX; o <<= 1) {
            int n = (t >= o) ? hist[t - o] : 0;
            __syncthreads();
            if (t >= o) hist[t] += n;
            __syncthreads();
        }
        int incl = hist[t];
        bucketptr[t + 1] = incl;
        if (t == 0) bucketptr[0] = 0;
        bucketcur[t] = incl - v;
    }
    grid.sync();

    // phase 3: scatter edges into bucket regions of tmp
    hist[t] = 0;
    __syncthreads();
    for (int e = bid * BLK + t; e < E; e += gstride)
        atomicAdd(&hist[dstIdx[e] >> 6], 1);
    __syncthreads();
    {
        int c = hist[t];
        base[t] = c ? atomicAdd(&bucketcur[t], c) : 0;
        hist[t] = 0;
    }
    __syncthreads();
    for (int e = bid * BLK + t; e < E; e += gstride) {
        int d = dstIdx[e];
        int bkt = d >> 6;
        int off = atomicAdd(&hist[bkt], 1);
        tmp[base[bkt] + off] = make_uint2((unsigned)srcIdx[e] | ((unsigned)(d & 63) << 16),
                                          __float_as_uint(ew[e]));
    }
    grid.sync();

    // phase 4: per-bucket local sort -> fin + rowptr + deginv (blocks 0..NB-1)
    if (bid < NB) {
        int s = bucketptr[bid], e2 = bucketptr[bid + 1];
        if (t < 64) hist[t] = 0;
        __syncthreads();
        for (int i = s + t; i < e2; i += BLK)
            atomicAdd(&hist[(tmp[i].x >> 16) & 63], 1);
        __syncthreads();
        if (t < 64) {
            int v = hist[t];
            int incl = v;
            for (int o = 1; o < 64; o <<= 1) {
                int n = __shfl_up(incl, o, 64);
                if (t >= o) incl += n;
            }
            int excl = incl - v;
            int d = (bid << 6) + t;
            if (d < N) {
                rowptr[d] = s + excl;
                deginv[d] = rsqrtf((float)v + 1.0f);
                if (d == N - 1) rowptr[N] = E;
            }
            base[t] = s + excl;
        }
        __syncthreads();
        for (int i = s + t; i < e2; i += BLK) {
            uint2 v = tmp[i];
            int dl = (v.x >> 16) & 63;
            int pos = atomicAdd(&base[dl], 1);
            fin[pos] = (v.x & 0xffffu) | (bf16bits(__uint_as_float(v.y)) << 16);
        }
    }
    grid.sync();

    // phase 5: xs[n] = packed bf16 pairs of x[n] * deginv[n]
    int N64 = N * 64;
    for (int idx = bid * BLK + t; idx < N64; idx += gstride) {
        float2 xv = ((const float2*)x)[idx];
        float sc = deginv[idx >> 6];
        xs[idx] = bf16bits(xv.x * sc) | (bf16bits(xv.y * sc) << 16);
    }
}

// ---- K2: fused aggregation + linear + GELU + LayerNorm. 2 nodes / block. ----
__global__ __launch_bounds__(256) void fused_node(
    const float* __restrict__ x, const unsigned int* __restrict__ xs,
    const int* __restrict__ rowptr, const unsigned int* __restrict__ fin,
    const float* __restrict__ deginv, const float* __restrict__ W,
    const float* __restrict__ bias, const float* __restrict__ gamma,
    const float* __restrict__ beta, float* __restrict__ out, int N) {
    int t = threadIdx.x;
    int nh = t >> 7;        // which of the block's 2 nodes
    int tt = t & 127;       // feature
    int w = (t >> 6) & 1;   // wave within node
    int l = t & 63;         // lane
    int node = blockIdx.x * 2 + nh;
    bool valid = node < N;
    int rs = 0, re = 0;
    if (valid) { rs = rowptr[node]; re = rowptr[node + 1]; }

    // wave w takes a contiguous half of the edge list (uniform fin addresses)
    int len = re - rs;
    int half = (len + 1) >> 1;
    int beg = rs + half * w;
    int end = w ? re : rs + half;

    float acc0 = 0.0f, acc1 = 0.0f;
    int i = beg;
    while (i + 16 <= end) {
        unsigned p[16];
#pragma unroll
        for (int j = 0; j < 16; ++j) p[j] = fin[i + j];
#pragma unroll
        for (int j = 0; j < 16; ++j) {
            float wt = __uint_as_float(p[j] & 0xffff0000u);
            unsigned xp = xs[(p[j] & 0xffffu) * 64u + (unsigned)l];
            acc0 = fmaf(__uint_as_float(xp << 16), wt, acc0);
            acc1 = fmaf(__uint_as_float(xp & 0xffff0000u), wt, acc1);
        }
        i += 16;
    }
    for (; i + 4 <= end; i += 4) {
        unsigned p[4];
#pragma unroll
        for (int j = 0; j < 4; ++j) p[j] = fin[i + j];
#pragma unroll
        for (int j = 0; j < 4; ++j) {
            float wt = __uint_as_float(p[j] & 0xffff0000u);
            unsigned xp = xs[(p[j] & 0xffffu) * 64u + (unsigned)l];
            acc0 = fmaf(__uint_as_float(xp << 16), wt, acc0);
            acc1 = fmaf(__uint_as_float(xp & 0xffff0000u), wt, acc1);
        }
    }
    for (; i < end; ++i) {
        unsigned p = fin[i];
        float wt = __uint_as_float(p & 0xffff0000u);
        unsigned xp = xs[(p & 0xffffu) * 64u + (unsigned)l];
        acc0 = fmaf(__uint_as_float(xp << 16), wt, acc0);
        acc1 = fmaf(__uint_as_float(xp & 0xffff0000u), wt, acc1);
    }

    __shared__ float part[2][2][D];
    part[nh][w][2 * l] = acc0;
    part[nh][w][2 * l + 1] = acc1;
    __syncthreads();

    __shared__ float agg_s[2][D];
    float aggv = 0.0f;
    if (valid) aggv = (part[nh][0][tt] + part[nh][1][tt]) * deginv[node] + x[node * D + tt];
    agg_s[nh][tt] = aggv;
    __syncthreads();

    float h = bias[tt];
#pragma unroll 8
    for (int k = 0; k < D; ++k)
        h = fmaf(agg_s[nh][k], W[k * D + tt], h);

    h = 0.5f * h * (1.0f + erff(h * 0.70710678118654752f));

    float v1 = h, v2 = h * h;
#pragma unroll
    for (int o = 32; o > 0; o >>= 1) {
        v1 += __shfl_xor(v1, o, 64);
        v2 += __shfl_xor(v2, o, 64);
    }
    __shared__ float s1s[2][2], s2s[2][2];
    if (l == 0) { s1s[nh][w] = v1; s2s[nh][w] = v2; }
    __syncthreads();
    float s1 = s1s[nh][0] + s1s[nh][1];
    float s2 = s2s[nh][0] + s2s[nh][1];
    float mu = s1 * (1.0f / D);
    float var = s2 * (1.0f / D) - mu * mu;
    float r = rsqrtf(var + 1e-5f);
    if (valid) out[node * D + tt] = (h - mu) * r * gamma[tt] + beta[tt];
}

static inline size_t align256(size_t v) { return (v + 255) & ~(size_t)255; }

extern "C" void kernel_launch(void* const* d_in, const int* in_sizes, int n_in,
                              void* d_out, int out_size, void* d_ws, size_t ws_size,
                              hipStream_t stream) {
    const float* x     = (const float*)d_in[0];
    const int*   ei    = (const int*)d_in[1];
    const float* ew    = (const float*)d_in[2];
    const float* W     = (const float*)d_in[3];
    const float* b     = (const float*)d_in[4];
    const float* gamma = (const float*)d_in[5];
    const float* beta  = (const float*)d_in[6];
    float* out = (float*)d_out;

    const int E = in_sizes[2];       // 640000
    const int N = in_sizes[0] / D;   // 10000
    const int NB = (N + 63) >> 6;    // 157 buckets
    const int* srcIdx = ei;
    const int* dstIdx = ei + E;

    char* ws = (char*)d_ws;
    size_t off = 0;
    int* bucketcnt = (int*)(ws + off);      off += align256((size_t)NBMAX * 4);
    int* bucketptr = (int*)(ws + off);      off += align256((size_t)(NBMAX + 1) * 4);
    int* bucketcur = (int*)(ws + off);      off += align256((size_t)NBMAX * 4);
    int* rowptr = (int*)(ws + off);         off += align256((size_t)(N + 1) * 4);
    float* deginv = (float*)(ws + off);     off += align256((size_t)N * 4);
    uint2* tmp = (uint2*)(ws + off);        off += align256((size_t)E * 8);
    unsigned int* fin = (unsigned int*)(ws + off);  off += align256((size_t)E * 4);
    unsigned int* xs = (unsigned int*)(ws + off);   off += align256((size_t)N * 64 * 4);
    (void)ws_size; (void)n_in; (void)out_size;

    {
        const float* ax = x;
        const int* asrc = srcIdx;
        const int* adst = dstIdx;
        const float* aew = ew;
        int aN = N, aE = E, aNB = NB;
        void* args[] = {
            (void*)&ax, (void*)&asrc, (void*)&adst, (void*)&aew,
            (void*)&bucketcnt, (void*)&bucketptr, (void*)&bucketcur,
            (void*)&tmp, (void*)&fin, (void*)&rowptr, (void*)&deginv, (void*)&xs,
            (void*)&aN, (void*)&aE, (void*)&aNB
        };
        hipLaunchCooperativeKernel((void*)build_all, dim3(GRID_BUILD), dim3(BLK),
                                   args, 0, stream);
    }
    fused_node<<<(N + 1) / 2, 256, 0, stream>>>(x, xs, rowptr, fin, deginv, W, b,
                                                gamma, beta, out, N);
}